// Round 11
// baseline (447.074 us; speedup 1.0000x reference)
//
#include <hip/hip_runtime.h>
#include <stdint.h>

#define QN    300
#define WN    10
#define CD    640
#define IJ    196
#define MROWS 1960              // WN*IJ
#define NTOT  58800             // QN*IJ
#define OUTQ  384160            // MROWS*IJ
#define EPSV  1e-8f

#define BM    256
#define BN    256
#define BK    32
#define NTK   (CD / BK)                // 20 K-tiles
#define BUFB  8192                     // ushorts per B buffer (256 rows x 32)

#define MT_TILES 8                     // m tiles of 256 (pad 2048)
#define NT_TILES 230                   // n tiles of 256 (pad 58880)
#define NWG      (MT_TILES * NT_TILES) // 1840, divisible by 8
#define CPX      (NWG / 8)             // 230

typedef __attribute__((ext_vector_type(8))) short bf16x8;
typedef __attribute__((ext_vector_type(4))) float f32x4;

__device__ __forceinline__ unsigned short f2bf(float f) {
    uint32_t u = __float_as_uint(f);
    u += 0x7FFFu + ((u >> 16) & 1u);   // RNE
    return (unsigned short)(u >> 16);
}

__device__ __forceinline__ void gload16(const void* g, void* l) {
    __builtin_amdgcn_global_load_lds(
        (const __attribute__((address_space(1))) void*)g,
        (__attribute__((address_space(3))) void*)l,
        16, 0, 0);
}

// ---------------------------------------------------------------------------
// Combined pre-pass (ONE launch): X[b][640][196] fp32 -> XT[row][640] bf16
// (k contiguous), swizzle baked per 16B unit within each 4-unit (32-elem)
// K-group: stored_unit = (u&12) | ((u&3) ^ ((row>>1)&3))  [BK=32 key,
// verified 0 bank conflicts in round 9].  Plus fp32 norms.
// grid = (4, 310): y<300 -> query, else proto.
// ---------------------------------------------------------------------------
__global__ __launch_bounds__(256)
void prep_all(const float* __restrict__ proto, const float* __restrict__ query,
              uint4* __restrict__ pT, uint4* __restrict__ qT,
              float* __restrict__ pn, float* __restrict__ qn)
{
    __shared__ float T[128][65];
    __shared__ float ssL[64][17];

    const int bi = blockIdx.y;
    const bool isQ = (bi < QN);
    const int b  = isQ ? bi : bi - QN;
    const float* Xb = (isQ ? query : proto) + (size_t)b * (CD * IJ);
    uint4* XT   = isQ ? qT : pT;
    float* nrm  = isQ ? qn : pn;
    const int rowbase = b * IJ;

    const int i0 = blockIdx.x * 64;
    const int t  = threadIdx.x;

    const int cg = t >> 4;
    const int i4 = (t & 15) * 4;
    const int iv = i0 + i4;
    const bool liv = (iv <= IJ - 4);

    const int u   = t & 15;
    const int ilb = (t >> 4) * 4;

    float ss[4] = {0.f, 0.f, 0.f, 0.f};

    for (int cc = 0; cc < CD / 128; ++cc) {
        #pragma unroll
        for (int pass = 0; pass < 8; ++pass) {
            int cl = pass * 16 + cg;
            int c  = cc * 128 + cl;
            float4 v = make_float4(0.f, 0.f, 0.f, 0.f);
            if (liv) v = *(const float4*)&Xb[(size_t)c * IJ + iv];
            T[cl][i4 + 0] = v.x; T[cl][i4 + 1] = v.y;
            T[cl][i4 + 2] = v.z; T[cl][i4 + 3] = v.w;
        }
        __syncthreads();
        #pragma unroll
        for (int j = 0; j < 4; ++j) {
            int il = ilb + j;
            float v[8];
            #pragma unroll
            for (int r = 0; r < 8; ++r) { v[r] = T[u * 8 + r][il]; ss[j] += v[r] * v[r]; }
            int ig = i0 + il;
            if (ig < IJ) {
                union { unsigned short s[8]; uint4 q; } pk;
                #pragma unroll
                for (int r = 0; r < 8; ++r) pk.s[r] = f2bf(v[r]);
                int rowg = rowbase + ig;
                int us = (u & 12) | ((u & 3) ^ ((rowg >> 1) & 3));
                XT[(size_t)rowg * (CD / 8) + cc * 16 + us] = pk.q;
            }
        }
        __syncthreads();
    }

    #pragma unroll
    for (int j = 0; j < 4; ++j) ssL[ilb + j][u] = ss[j];
    __syncthreads();
    if (t < 64) {
        int ig = i0 + t;
        if (ig < IJ) {
            float s = 0.f;
            #pragma unroll
            for (int k = 0; k < 16; ++k) s += ssL[t][k];
            nrm[rowbase + ig] = sqrtf(s);
        }
    }
}

// ---------------------------------------------------------------------------
// GEMM: C[m][n] = sum_c AT[m][c]*BT[n][c].  256x256 tile, 8 waves (2M x 4N),
// per-wave 128x64 (acc[8][4] of 16x16x32), BK=32, 20 K-tiles.
//
// A DIRECT FROM L2 -> REGISTERS (A matrix = 2.5 MB, L2-resident per XCD):
// each wave loads its 8 A-fragments (16B/lane, per-lane addr with baked
// swizzle XOR) one K-tile ahead into a double-buffered reg set.  LDS holds
// ONLY B: 4 x 16 KB circular buffers, staged 2 K-tiles ahead via
// global_load_lds.  One phase per K-tile:
//   { stage B(t+2) (2 gload16) | load A(t+1) (8 dwordx4) | vmcnt(10) |
//     barrier | sched_barrier | 4 ds_read_b128 B(t) | 32 MFMA (setprio) }
// vmcnt(10) = this phase's 10 issues stay in flight; everything older
// (A(t), B(t)'s staging) is landed; barrier publishes other waves' staging.
// WAR audit: stage target buf[(t+2)%4] was last read at phase t-2; every
// wave's phase t-2 reads complete before its own phase t-1 barrier arrival,
// and the stage is issued after passing that barrier -> safe.  Tail stages
// (t=18,19) read <=7 uint4 past pT/qT end (into adjacent ws regions,
// benign) into dead buffers, drained by the final vmcnt(0).
// Swapped-operand MFMA -> float4 epilogue stores (round-8 verified).
// ---------------------------------------------------------------------------
__global__ __launch_bounds__(512, 2)
void gemm_kernel(const uint4* __restrict__ AT, const uint4* __restrict__ BT,
                 const float* __restrict__ pn, const float* __restrict__ qn,
                 float* __restrict__ out)
{
    __shared__ unsigned short lds[4 * BUFB];   // 64 KB (B only)

    const int bid = blockIdx.x;
    const int swz = (bid & 7) * CPX + (bid >> 3);   // bijective (1840%8==0)
    const int mt  = swz & (MT_TILES - 1);
    const int nt  = swz >> 3;
    const int m0  = mt * BM;
    const int n0  = nt * BN;

    const int t  = threadIdx.x;
    const int w  = t >> 6, l = t & 63;
    const int fr = l & 15, fq = l >> 4;
    const int wm0 = (w >> 2) * 128;   // 2 M-waves
    const int wn0 = (w & 3) * 64;     // 4 N-waves

    // ---- B staging (2 gload16/wave/K-tile; call c covers rows c*128..+127)
    const int srow = w * 16 + (l >> 2);
    const int su   = l & 3;
    int rb0 = n0 +       srow; if (rb0 > NTOT - 1) rb0 = NTOT - 1;
    int rb1 = n0 + 128 + srow; if (rb1 > NTOT - 1) rb1 = NTOT - 1;
    const uint4* gb0 = BT + (size_t)rb0 * 80 + su;
    const uint4* gb1 = BT + (size_t)rb1 * 80 + su;
    const int lb0 = w * 512;            // ushort offset within buffer
    const int lb1 = 4096 + w * 512;

    // ---- A direct: 8 per-lane fragment pointers (swizzle XOR baked in addr)
    const uint4* pa[8];
    #pragma unroll
    for (int i = 0; i < 8; ++i) {
        int row = m0 + wm0 + i * 16 + fr; if (row > MROWS - 1) row = MROWS - 1;
        pa[i] = AT + (size_t)row * 80 + (fq ^ ((row >> 1) & 3));
    }

    // ---- B fragment LDS offsets (loop-invariant; key matches prep bake)
    int foB[4];
    #pragma unroll
    for (int i = 0; i < 4; ++i) {
        int row = wn0 + i * 16 + fr;
        foB[i] = row * 32 + ((fq ^ ((row >> 1) & 3)) << 3);
    }

    f32x4 acc[8][4];
    #pragma unroll
    for (int a = 0; a < 8; ++a)
        #pragma unroll
        for (int bb = 0; bb < 4; ++bb)
            acc[a][bb] = (f32x4){0.f, 0.f, 0.f, 0.f};

#define STB(BUF)                                                          \
    gload16(gb0, (char*)&lds[(BUF) * BUFB + lb0]); gb0 += 4;              \
    gload16(gb1, (char*)&lds[(BUF) * BUFB + lb1]); gb1 += 4;

#define LDA(AF)                                                           \
    _Pragma("unroll")                                                     \
    for (int i = 0; i < 8; ++i) { AF[i] = *(const bf16x8*)pa[i]; pa[i] += 4; }

#define BAR    __builtin_amdgcn_s_barrier()
#define SBAR0  __builtin_amdgcn_sched_barrier(0)
#define VMC(N) asm volatile("s_waitcnt vmcnt(" #N ")" ::: "memory")
#define PRIO1  __builtin_amdgcn_s_setprio(1)
#define PRIO0  __builtin_amdgcn_s_setprio(0)

#define PH(BUF, AFC, AFN)                                                 \
  { STB((BUF + 2) & 3); LDA(AFN);                                         \
    VMC(10); BAR; SBAR0;                                                  \
    bf16x8 bf[4];                                                         \
    _Pragma("unroll")                                                     \
    for (int nf = 0; nf < 4; ++nf)                                        \
        bf[nf] = *(const bf16x8*)&lds[(BUF) * BUFB + foB[nf]];            \
    PRIO1;                                                                \
    _Pragma("unroll")                                                     \
    for (int mm = 0; mm < 8; ++mm)                                        \
        _Pragma("unroll")                                                 \
        for (int nn = 0; nn < 4; ++nn)                                    \
            acc[mm][nn] = __builtin_amdgcn_mfma_f32_16x16x32_bf16(        \
                bf[nn], AFC[mm], acc[mm][nn], 0, 0, 0);                   \
    PRIO0; }

    bf16x8 afA[8], afB[8];

    // ---- prologue: B(0)->buf0, B(1)->buf1, A(0)->afA.  12 outstanding;
    // VMC(8) drains B(0),B(1); A(0)'s 8 stay in flight (compiler waits on
    // the afA regs before first MFMA use).
    STB(0); STB(1); LDA(afA);
    VMC(8); BAR;

    // ---- 20 phases, 4-unrolled (buffer %4, A-regs parity %2)
    for (int it = 0; it < 5; ++it) {
        PH(0, afA, afB)
        PH(1, afB, afA)
        PH(2, afA, afB)
        PH(3, afB, afA)
    }

    VMC(0);   // drain tail garbage stages/loads before epilogue

#undef PH
#undef STB
#undef LDA
#undef BAR
#undef SBAR0
#undef VMC
#undef PRIO1
#undef PRIO0

    // ---- epilogue (swapped D-layout, round-8 verified):
    //   m = m0 + wm0 + tm*16 + fr          (D col)
    //   n = n0 + wn0 + tn*16 + fq*4 + e    (D rows, e=0..3 -> float4)
    float4 rqv4[4];
    int    nok[4];
    size_t ob[4];
    #pragma unroll
    for (int tn = 0; tn < 4; ++tn) {
        int n = n0 + wn0 + tn * 16 + fq * 4;
        nok[tn] = (n < NTOT);
        int nc = nok[tn] ? n : NTOT - 4;
        int q  = nc / IJ;
        int j  = nc - q * IJ;
        rqv4[tn] = *(const float4*)&qn[nc];
        ob[tn] = (size_t)q * OUTQ + j;
    }
    #pragma unroll
    for (int tm = 0; tm < 8; ++tm) {
        int m = m0 + wm0 + tm * 16 + fr;
        if (m < MROWS) {
            float rp = pn[m];
            #pragma unroll
            for (int tn = 0; tn < 4; ++tn) {
                if (nok[tn]) {
                    f32x4 a = acc[tm][tn];
                    float4 o;
                    o.x = a[0] * __builtin_amdgcn_rcpf(fmaxf(rp * rqv4[tn].x, EPSV));
                    o.y = a[1] * __builtin_amdgcn_rcpf(fmaxf(rp * rqv4[tn].y, EPSV));
                    o.z = a[2] * __builtin_amdgcn_rcpf(fmaxf(rp * rqv4[tn].z, EPSV));
                    o.w = a[3] * __builtin_amdgcn_rcpf(fmaxf(rp * rqv4[tn].w, EPSV));
                    *(float4*)&out[ob[tn] + (size_t)m * IJ] = o;
                }
            }
        }
    }
}

// ---------------------------------------------------------------------------
// Fallback (round-1 kernel, known-passing) if ws_size is insufficient.
// ---------------------------------------------------------------------------
#define BMF 128
#define BNF 224
#define LPAD 40
__global__ __launch_bounds__(512, 4)
void sim_fallback(const float* __restrict__ proto,
                  const float* __restrict__ query,
                  float* __restrict__ out)
{
    __shared__ unsigned short As[BMF][LPAD];
    __shared__ unsigned short Bs[BNF][LPAD];
    __shared__ float redA[4][BMF];
    __shared__ float redB[2][BNF];
    __shared__ float rpS[BMF];
    __shared__ float rqS[BNF];

    const int tid = threadIdx.x;
    const int m0  = blockIdx.x * BMF;
    const int q   = blockIdx.y;

    const int mA  = tid & (BMF - 1);
    const int krA = tid >> 7;
    const int wiA = m0 + mA;
    const bool va = (wiA < MROWS);
    const int wA  = va ? (wiA / IJ) : 0;
    const int iA  = va ? (wiA - wA * IJ) : 0;
    const float* pA = proto + wA * (CD * IJ) + iA;

    const bool tb  = (tid < 448);
    const int jB   = tb ? (tid % BNF) : 0;
    const int krB  = tb ? (tid / BNF) : 0;
    const bool vb  = tb && (jB < IJ);
    const float* qB = query + q * (CD * IJ) + jB;

    float ssA = 0.f, ssB = 0.f;

    const int wv   = tid >> 6;
    const int lane = tid & 63;
    const int wm0  = (wv >> 1) * 32;
    const int wn0  = (wv & 1) * 112;
    const int fr   = lane & 15;
    const int fq   = lane >> 4;

    f32x4 acc[2][7];
    #pragma unroll
    for (int a = 0; a < 2; a++)
        #pragma unroll
        for (int b = 0; b < 7; b++)
            acc[a][b] = (f32x4){0.f, 0.f, 0.f, 0.f};

    for (int it = 0; it < CD / 32; ++it) {
        const int c0 = it * 32;
        {
            float v[8];
            #pragma unroll
            for (int e = 0; e < 8; e++) {
                int c = c0 + krA * 8 + e;
                v[e] = va ? pA[c * IJ] : 0.f;
            }
            #pragma unroll
            for (int e = 0; e < 8; e++) ssA += v[e] * v[e];
            union { unsigned short s[8]; uint4 u; } pk;
            #pragma unroll
            for (int e = 0; e < 8; e++) pk.s[e] = f2bf(v[e]);
            *(uint4*)&As[mA][krA * 8] = pk.u;
        }
        if (tb) {
            #pragma unroll
            for (int h = 0; h < 2; ++h) {
                float v[8];
                #pragma unroll
                for (int e = 0; e < 8; e++) {
                    int c = c0 + krB * 16 + h * 8 + e;
                    v[e] = vb ? qB[c * IJ] : 0.f;
                }
                #pragma unroll
                for (int e = 0; e < 8; e++) ssB += v[e] * v[e];
                union { unsigned short s[8]; uint4 u; } pk;
                #pragma unroll
                for (int e = 0; e < 8; e++) pk.s[e] = f2bf(v[e]);
                *(uint4*)&Bs[jB][krB * 16 + h * 8] = pk.u;
            }
        }
        __syncthreads();
        bf16x8 af[2], bfv[7];
        #pragma unroll
        for (int tm = 0; tm < 2; tm++)
            af[tm] = *(const bf16x8*)&As[wm0 + tm * 16 + fr][fq * 8];
        #pragma unroll
        for (int tn = 0; tn < 7; tn++)
            bfv[tn] = *(const bf16x8*)&Bs[wn0 + tn * 16 + fr][fq * 8];
        #pragma unroll
        for (int tm = 0; tm < 2; tm++)
            #pragma unroll
            for (int tn = 0; tn < 7; tn++)
                acc[tm][tn] = __builtin_amdgcn_mfma_f32_16x16x32_bf16(
                    af[tm], bfv[tn], acc[tm][tn], 0, 0, 0);
        __syncthreads();
    }

    redA[krA][mA] = ssA;
    if (tb) redB[krB][jB] = ssB;
    __syncthreads();
    if (tid < BMF) {
        rpS[tid] = sqrtf(redA[0][tid] + redA[1][tid] + redA[2][tid] + redA[3][tid]);
    } else if (tid >= 256 && tid < 256 + BNF) {
        int j = tid - 256;
        rqS[j] = sqrtf(redB[0][j] + redB[1][j]);
    }
    __syncthreads();

    #pragma unroll
    for (int tm = 0; tm < 2; tm++) {
        #pragma unroll
        for (int tn = 0; tn < 7; tn++) {
            #pragma unroll
            for (int r = 0; r < 4; r++) {
                int rl = wm0 + tm * 16 + fq * 4 + r;
                int cl = wn0 + tn * 16 + fr;
                int wi = m0 + rl;
                if (wi < MROWS && cl < IJ) {
                    float denom = fmaxf(rpS[rl] * rqS[cl], 1e-8f);
                    out[(size_t)(q * MROWS + wi) * IJ + cl] = acc[tm][tn][r] / denom;
                }
            }
        }
    }
}

// ---------------------------------------------------------------------------
extern "C" void kernel_launch(void* const* d_in, const int* in_sizes, int n_in,
                              void* d_out, int out_size, void* d_ws, size_t ws_size,
                              hipStream_t stream) {
    const float* proto = (const float*)d_in[0];
    const float* query = (const float*)d_in[1];
    float* out = (float*)d_out;

    // workspace layout
    const size_t off_pT = 0;                       // 1960*640*2 = 2,508,800
    const size_t off_qT = 2508800;                 // 58800*640*2 = 75,264,000
    const size_t off_pn = 77772800;                // 1960*4
    const size_t off_qn = 77780736;                // 58800*4
    const size_t need   = 78015936;

    if (ws_size < need) {
        dim3 grid((MROWS + BMF - 1) / BMF, QN);
        sim_fallback<<<grid, 512, 0, stream>>>(proto, query, out);
        return;
    }

    char* ws = (char*)d_ws;
    uint4* pT = (uint4*)(ws + off_pT);
    uint4* qT = (uint4*)(ws + off_qT);
    float* pn = (float*)(ws + off_pn);
    float* qn = (float*)(ws + off_qn);

    prep_all<<<dim3(4, QN + WN), 256, 0, stream>>>(proto, query, pT, qT, pn, qn);

    gemm_kernel<<<dim3(NWG), 512, 0, stream>>>(pT, qT, pn, qn, out);
}